// Round 7
// baseline (118.178 us; speedup 1.0000x reference)
//
#include <hip/hip_runtime.h>
#include <math.h>

#define D_ 96
#define L_ 4096
#define K_ 8
#define N_ 16
#define R_ 6
#define CDBL 38   // R + 2N
#define DL_ (D_ * L_)

#define REPN(M) M(0) M(1) M(2) M(3) M(4) M(5) M(6) M(7) \
                M(8) M(9) M(10) M(11) M(12) M(13) M(14) M(15)
#define REP8(M) M(0) M(1) M(2) M(3) M(4) M(5) M(6) M(7)

#if __has_builtin(__builtin_amdgcn_exp2f)
#define EXP2(x) __builtin_amdgcn_exp2f(x)
#else
#define EXP2(x) exp2f(x)
#endif

__device__ __forceinline__ float softplusf(float x) {
    return (x > 20.f) ? x : log1pf(__expf(x));
}

// source index within one channel's [64][64] image for direction k, flat pos l
__device__ __forceinline__ int src_index(int k, int l) {
    int h = l & 63, w = l >> 6;
    int lp = 4095 - l;
    int hp = lp & 63, wp = lp >> 6;
    switch (k) {
    case 0: return l;
    case 1: return (h << 6) + w;
    case 2: return lp;
    case 3: return (hp << 6) + wp;
    case 4: return (h << 6) + ((h + w) & 63);
    case 5: return (h << 6) + ((w - h) & 63);
    case 6: return (hp << 6) + ((hp + wp) & 63);
    default: return (hp << 6) + ((wp - hp) & 63);
    }
}

// ---------------- K_A: x_dbl = wproj @ cross_scan(x), gathers x inline ----------
// grid 512 = 8 k * 64 l-tiles of 64; block 256.
__global__ __launch_bounds__(256) void k_xdbl(const float* __restrict__ x,
                                              const float* __restrict__ wproj,
                                              float* __restrict__ xdbl) {
    __shared__ float tile[64][100];
    int bid = blockIdx.x;
    int swz = (bid & 7) * 64 + (bid >> 3);   // XCD swizzle: each XCD owns one k
    int k = swz >> 6;
    int l0 = (swz & 63) * 64;

    for (int e = threadIdx.x; e < D_ * 64; e += 256) {
        int d = e >> 6, li = e & 63;
        tile[li][d] = x[d * L_ + src_index(k, l0 + li)];
    }
    __syncthreads();

    int lt = threadIdx.x & 63;
    int cg = __builtin_amdgcn_readfirstlane(threadIdx.x >> 6);   // wave-uniform 0..3
    const float* wk = wproj + k * CDBL * D_;
    float acc[10];
    #pragma unroll
    for (int j = 0; j < 10; ++j) acc[j] = 0.f;
    for (int d4 = 0; d4 < D_; d4 += 4) {
        float4 tv = *(const float4*)&tile[lt][d4];
        #pragma unroll
        for (int j = 0; j < 10; ++j) {
            int c = cg + 4 * j;
            if (c < CDBL) {
                float4 wv = *(const float4*)&wk[c * D_ + d4];   // scalar addr -> s_load
                acc[j] = fmaf(tv.x, wv.x, acc[j]);
                acc[j] = fmaf(tv.y, wv.y, acc[j]);
                acc[j] = fmaf(tv.z, wv.z, acc[j]);
                acc[j] = fmaf(tv.w, wv.w, acc[j]);
            }
        }
    }
    #pragma unroll
    for (int j = 0; j < 10; ++j) {
        int c = cg + 4 * j;
        if (c < CDBL) xdbl[(k * CDBL + c) * L_ + l0 + lt] = acc[j];
    }
}

// ---------------- K_B: fused delta + selective scan (ALL-SCALAR state) --------
// v3: 512-thread blocks, 8 elem/thread, grid 768.
// Round-6 lesson: __launch_bounds__(512,6) acted as 6 BLOCKS/CU (CUDA
// semantics) -> 12 waves/EU -> VGPR cap 42 -> 84MB spill. (512,3) is safe
// under BOTH semantics: blocks/CU -> 24 waves/CU with cap 85; waves/EU ->
// cap 170 and runtime occupancy still 3 blocks/CU (grid 768 = 3/CU exactly).
// Named-scalar state only (rounds 2-4: arrays -> scratch). Per-n fences cap
// load hoisting (round-5 spill fix).

#if __has_builtin(__builtin_amdgcn_update_dpp)
#define HAVE_DPP 1
template<int CTRL, int RM>
__device__ __forceinline__ float updpp(float oldv, float src) {
    int r = __builtin_amdgcn_update_dpp(__builtin_bit_cast(int, oldv),
                                        __builtin_bit_cast(int, src),
                                        CTRL, RM, 0xF, false);
    return __builtin_bit_cast(float, r);
}
#else
#define HAVE_DPP 0
#endif

__global__ __launch_bounds__(512, 3) void k_scan(const float* __restrict__ xdbl,
                                                 const float* __restrict__ dtw,
                                                 const float* __restrict__ dtb,
                                                 const float* __restrict__ alogs,
                                                 const float* __restrict__ dsv_,
                                                 const float* __restrict__ x,
                                                 float* __restrict__ ys) {
    int bid = blockIdx.x;
    int k = bid & 7;                 // XCD swizzle: k == XCD id
    int d = bid >> 3;
    int kd = k * D_ + d;
    int t = threadIdx.x;
    int lane = t & 63, wv = t >> 6;  // wv in 0..7
    int l0t = t * 8;

    __shared__ float An2_s[16];
    __shared__ float agg_a[8][16], agg_b[8][16];
    if (t < 16)
        An2_s[t] = -expf(alogs[kd * N_ + t]) * 1.44269504088896340736f;

#define DECL(n) float sA##n, sB##n;
    REPN(DECL)
#undef DECL
#define DECL(i) float d##i, u##i, y##i;
    REP8(DECL)
#undef DECL

    // ---- delta (fused): 8 elements ----
    const float* xr = xdbl + k * CDBL * L_;
    const float2* wp2 = (const float2*)(dtw + kd * R_);
    const float2 w01 = wp2[0], w23 = wp2[1], w45 = wp2[2];
    const float bias = dtb[kd];
    const float dval = dsv_[kd];
#define DLTQ(j, i0, i1, i2, i3) { \
    const float4 r0 = *(const float4*)(xr + 0 * L_ + l0t + j * 4); \
    const float4 r1 = *(const float4*)(xr + 1 * L_ + l0t + j * 4); \
    const float4 r2 = *(const float4*)(xr + 2 * L_ + l0t + j * 4); \
    const float4 r3 = *(const float4*)(xr + 3 * L_ + l0t + j * 4); \
    const float4 r4 = *(const float4*)(xr + 4 * L_ + l0t + j * 4); \
    const float4 r5 = *(const float4*)(xr + 5 * L_ + l0t + j * 4); \
    float s; \
    s = fmaf(w01.x, r0.x, bias); s = fmaf(w01.y, r1.x, s); s = fmaf(w23.x, r2.x, s); \
    s = fmaf(w23.y, r3.x, s); s = fmaf(w45.x, r4.x, s); s = fmaf(w45.y, r5.x, s); \
    d##i0 = softplusf(s); \
    s = fmaf(w01.x, r0.y, bias); s = fmaf(w01.y, r1.y, s); s = fmaf(w23.x, r2.y, s); \
    s = fmaf(w23.y, r3.y, s); s = fmaf(w45.x, r4.y, s); s = fmaf(w45.y, r5.y, s); \
    d##i1 = softplusf(s); \
    s = fmaf(w01.x, r0.z, bias); s = fmaf(w01.y, r1.z, s); s = fmaf(w23.x, r2.z, s); \
    s = fmaf(w23.y, r3.z, s); s = fmaf(w45.x, r4.z, s); s = fmaf(w45.y, r5.z, s); \
    d##i2 = softplusf(s); \
    s = fmaf(w01.x, r0.w, bias); s = fmaf(w01.y, r1.w, s); s = fmaf(w23.x, r2.w, s); \
    s = fmaf(w23.y, r3.w, s); s = fmaf(w45.x, r4.w, s); s = fmaf(w45.y, r5.w, s); \
    d##i3 = softplusf(s); }
    DLTQ(0, 0, 1, 2, 3)
    DLTQ(1, 4, 5, 6, 7)
#undef DLTQ

    // ---- u gather; y = Ds*u; u -> du = d*u ----
    const float* xd = x + d * L_;
#define UG(i) u##i = xd[src_index(k, l0t + i)]; y##i = dval * u##i; u##i *= d##i;
    REP8(UG)
#undef UG

    __syncthreads();   // An2_s ready

    const float* Bptr = xdbl + (k * CDBL + R_) * L_ + l0t;
    const float* Cptr = Bptr + N_ * L_;

    // ---- Phase A: per-n local (a,b) segment aggregates ----
#define PHA_E(i, Bc) { float e = EXP2(d##i * An2); \
    rb = fmaf(e, rb, u##i * (Bc)); ra *= e; }
#define PHA(n) { \
    const float An2 = An2_s[n]; \
    const float* Bn = Bptr + n * L_; \
    const float4 b0 = *(const float4*)(Bn), b1 = *(const float4*)(Bn + 4); \
    float ra = 1.f, rb = 0.f; \
    PHA_E(0, b0.x) PHA_E(1, b0.y) PHA_E(2, b0.z) PHA_E(3, b0.w) \
    PHA_E(4, b1.x) PHA_E(5, b1.y) PHA_E(6, b1.z) PHA_E(7, b1.w) \
    sA##n = ra; sB##n = rb; \
    asm volatile("" ::: "memory"); }
    REPN(PHA)
#undef PHA
#undef PHA_E

    // ---- Phase B: 64-lane inclusive scan of 16 scalar (a,b) pairs ----
#if HAVE_DPP
#define SSTN(n) { float pa = updpp<SC_CTRL, SC_RM>(1.f, sA##n); \
                  float pb = updpp<SC_CTRL, SC_RM>(0.f, sB##n); \
                  sB##n = fmaf(sA##n, pb, sB##n); sA##n *= pa; }
#define SC_CTRL 0x111
#define SC_RM 0xF
    REPN(SSTN)            // row_shr:1
#undef SC_CTRL
#undef SC_RM
#define SC_CTRL 0x112
#define SC_RM 0xF
    REPN(SSTN)            // row_shr:2
#undef SC_CTRL
#undef SC_RM
#define SC_CTRL 0x114
#define SC_RM 0xF
    REPN(SSTN)            // row_shr:4
#undef SC_CTRL
#undef SC_RM
#define SC_CTRL 0x118
#define SC_RM 0xF
    REPN(SSTN)            // row_shr:8
#undef SC_CTRL
#undef SC_RM
#define SC_CTRL 0x142
#define SC_RM 0xA
    REPN(SSTN)            // row_bcast:15 -> rows 1,3
#undef SC_CTRL
#undef SC_RM
#define SC_CTRL 0x143
#define SC_RM 0xC
    REPN(SSTN)            // row_bcast:31 -> rows 2,3
#undef SC_CTRL
#undef SC_RM
#undef SSTN
#else
#define PBF(n) { float pa = __shfl_up(sA##n, off); float pb = __shfl_up(sB##n, off); \
    if (lane >= off) { sB##n = fmaf(sA##n, pb, sB##n); sA##n *= pa; } }
    for (int off = 1; off < 64; off <<= 1) { REPN(PBF) }
#undef PBF
#endif

    // exclusive prefix per lane + wave aggregates
#define PPREF(n) { float ia = sA##n, ib = sB##n; \
    float ea = __shfl_up(ia, 1); float eb = __shfl_up(ib, 1); \
    if (lane == 0) { ea = 1.f; eb = 0.f; } \
    if (lane == 63) { agg_a[wv][n] = ia; agg_b[wv][n] = ib; } \
    sA##n = ea; sB##n = eb; }
    REPN(PPREF)
#undef PPREF
    __syncthreads();

    // ---- Phase C: cross-wave carry -> h_enter per (thread, n), into sA ----
#define PC(n) { float cb = 0.f; \
    for (int w2 = 0; w2 < wv; ++w2) cb = fmaf(agg_a[w2][n], cb, agg_b[w2][n]); \
    sA##n = fmaf(sA##n, cb, sB##n); }
    REPN(PC)
#undef PC

    // ---- Phase D: plain recurrence from h_enter; y += C*h ----
#define PHD_E(i, Bc, Cc) { float e = EXP2(d##i * An2); \
    h = fmaf(e, h, u##i * (Bc)); y##i = fmaf((Cc), h, y##i); }
#define PHD(n) { \
    const float An2 = An2_s[n]; float h = sA##n; \
    const float* Bn = Bptr + n * L_; const float* Cn = Cptr + n * L_; \
    const float4 b0 = *(const float4*)(Bn), b1 = *(const float4*)(Bn + 4); \
    const float4 c0 = *(const float4*)(Cn), c1 = *(const float4*)(Cn + 4); \
    PHD_E(0, b0.x, c0.x) PHD_E(1, b0.y, c0.y) PHD_E(2, b0.z, c0.z) PHD_E(3, b0.w, c0.w) \
    PHD_E(4, b1.x, c1.x) PHD_E(5, b1.y, c1.y) PHD_E(6, b1.z, c1.z) PHD_E(7, b1.w, c1.w) \
    asm volatile("" ::: "memory"); }
    REPN(PHD)
#undef PHD
#undef PHD_E

    float* yp = ys + kd * L_ + l0t;
    {
        float4 o;
        o.x = y0; o.y = y1; o.z = y2; o.w = y3; *(float4*)(yp + 0) = o;
        o.x = y4; o.y = y5; o.z = y6; o.w = y7; *(float4*)(yp + 4) = o;
    }
}

// ---------------- K_C: cross_merge + LayerNorm fused ----------------
// grid 128 blocks x 32 positions; block 256
__global__ __launch_bounds__(256) void k_merge_ln(const float* __restrict__ ys,
                                                  const float* __restrict__ gamma,
                                                  const float* __restrict__ beta,
                                                  float* __restrict__ out) {
    __shared__ float sm[32][D_ + 1];
    __shared__ float mu_s[32], rs_s[32];
    int l0 = blockIdx.x * 32;
    for (int e = threadIdx.x; e < 32 * D_; e += 256) {
        int li = e & 31, d = e >> 5;
        int l = l0 + li;
        int h = l >> 6, w = l & 63;
        int i1 = (w << 6) + h;
        int i4 = (((w - h) & 63) << 6) + h;
        int i5 = (((w + h) & 63) << 6) + h;
        const float* bd = ys + d * L_;
        float v = bd[0 * DL_ + l] + bd[2 * DL_ + 4095 - l]
                + bd[1 * DL_ + i1] + bd[3 * DL_ + 4095 - i1]
                + bd[4 * DL_ + i4] + bd[6 * DL_ + 4095 - i4]
                + bd[5 * DL_ + i5] + bd[7 * DL_ + 4095 - i5];
        sm[li][d] = v;
    }
    __syncthreads();
    int li2 = threadIdx.x >> 3, sub = threadIdx.x & 7;
    float s = 0.f, sq = 0.f;
    for (int d = sub; d < D_; d += 8) {
        float v = sm[li2][d];
        s += v; sq = fmaf(v, v, sq);
    }
    s += __shfl_xor(s, 1); sq += __shfl_xor(sq, 1);
    s += __shfl_xor(s, 2); sq += __shfl_xor(sq, 2);
    s += __shfl_xor(s, 4); sq += __shfl_xor(sq, 4);
    if (sub == 0) {
        float mu = s * (1.f / 96.f);
        float var = sq * (1.f / 96.f) - mu * mu;
        mu_s[li2] = mu;
        rs_s[li2] = rsqrtf(var + 1e-5f);
    }
    __syncthreads();
    for (int e = threadIdx.x; e < 32 * D_; e += 256) {
        int li = e / D_, d = e - li * D_;
        float v = (sm[li][d] - mu_s[li]) * rs_s[li];
        out[(l0 + li) * D_ + d] = fmaf(v, gamma[d], beta[d]);
    }
}

extern "C" void kernel_launch(void* const* d_in, const int* in_sizes, int n_in,
                              void* d_out, int out_size, void* d_ws, size_t ws_size,
                              hipStream_t stream) {
    const float* x     = (const float*)d_in[0];
    const float* wproj = (const float*)d_in[1];
    const float* dtw   = (const float*)d_in[2];
    const float* dtb   = (const float*)d_in[3];
    const float* alogs = (const float*)d_in[4];
    const float* dsv   = (const float*)d_in[5];
    const float* gamma = (const float*)d_in[6];
    const float* beta  = (const float*)d_in[7];
    float* out = (float*)d_out;
    float* ws  = (float*)d_ws;

    float* xdbl = ws;                 // K*CDBL*L = 1,245,184 floats
    float* ysb  = ws + 1245184;       // K*D*L    = 3,145,728 floats

    hipLaunchKernelGGL(k_xdbl, dim3(512), dim3(256), 0, stream, x, wproj, xdbl);
    hipLaunchKernelGGL(k_scan, dim3(768), dim3(512), 0, stream,
                       xdbl, dtw, dtb, alogs, dsv, x, ysb);
    hipLaunchKernelGGL(k_merge_ln, dim3(128), dim3(256), 0, stream,
                       ysb, gamma, beta, out);
}

// Round 8
// 103.990 us; speedup vs baseline: 1.1364x; 1.1364x over previous
//
#include <hip/hip_runtime.h>
#include <math.h>

#define D_ 96
#define L_ 4096
#define K_ 8
#define N_ 16
#define R_ 6
#define CDBL 38   // R + 2N
#define DL_ (D_ * L_)

#define REPN(M) M(0) M(1) M(2) M(3) M(4) M(5) M(6) M(7) \
                M(8) M(9) M(10) M(11) M(12) M(13) M(14) M(15)
#define REP8(M) M(0) M(1) M(2) M(3) M(4) M(5) M(6) M(7)
#define FENCE asm volatile("" ::: "memory");

#if __has_builtin(__builtin_amdgcn_exp2f)
#define EXP2(x) __builtin_amdgcn_exp2f(x)
#else
#define EXP2(x) exp2f(x)
#endif
#if __has_builtin(__builtin_amdgcn_logf)
#define LOG2F(x) __builtin_amdgcn_logf(x)
#else
#define LOG2F(x) __log2f(x)
#endif

#define LOG2E 1.44269504088896340736f
#define LN2F  0.69314718055994530942f

// source index within one channel's [64][64] image for direction k, flat pos l
__device__ __forceinline__ int src_index(int k, int l) {
    int h = l & 63, w = l >> 6;
    int lp = 4095 - l;
    int hp = lp & 63, wp = lp >> 6;
    switch (k) {
    case 0: return l;
    case 1: return (h << 6) + w;
    case 2: return lp;
    case 3: return (hp << 6) + wp;
    case 4: return (h << 6) + ((h + w) & 63);
    case 5: return (h << 6) + ((w - h) & 63);
    case 6: return (hp << 6) + ((hp + wp) & 63);
    default: return (hp << 6) + ((wp - hp) & 63);
    }
}

// ---------------- K_A: x_dbl = wproj @ cross_scan(x), gathers x inline ----------
// grid 512 = 8 k * 64 l-tiles of 64; block 256.
__global__ __launch_bounds__(256) void k_xdbl(const float* __restrict__ x,
                                              const float* __restrict__ wproj,
                                              float* __restrict__ xdbl) {
    __shared__ float tile[64][100];
    int bid = blockIdx.x;
    int swz = (bid & 7) * 64 + (bid >> 3);   // XCD swizzle: each XCD owns one k
    int k = swz >> 6;
    int l0 = (swz & 63) * 64;

    for (int e = threadIdx.x; e < D_ * 64; e += 256) {
        int d = e >> 6, li = e & 63;
        tile[li][d] = x[d * L_ + src_index(k, l0 + li)];
    }
    __syncthreads();

    int lt = threadIdx.x & 63;
    int cg = __builtin_amdgcn_readfirstlane(threadIdx.x >> 6);   // wave-uniform 0..3
    const float* wk = wproj + k * CDBL * D_;
    float acc[10];
    #pragma unroll
    for (int j = 0; j < 10; ++j) acc[j] = 0.f;
    for (int d4 = 0; d4 < D_; d4 += 4) {
        float4 tv = *(const float4*)&tile[lt][d4];
        #pragma unroll
        for (int j = 0; j < 10; ++j) {
            int c = cg + 4 * j;
            if (c < CDBL) {
                float4 wv = *(const float4*)&wk[c * D_ + d4];   // scalar addr -> s_load
                acc[j] = fmaf(tv.x, wv.x, acc[j]);
                acc[j] = fmaf(tv.y, wv.y, acc[j]);
                acc[j] = fmaf(tv.z, wv.z, acc[j]);
                acc[j] = fmaf(tv.w, wv.w, acc[j]);
            }
        }
    }
    #pragma unroll
    for (int j = 0; j < 10; ++j) {
        int c = cg + 4 * j;
        if (c < CDBL) xdbl[(k * CDBL + c) * L_ + l0 + lt] = acc[j];
    }
}

// ---------------- K_B: fused delta + selective scan (ALL-SCALAR state) --------
// v4: 512 threads, 8 elem/thread, grid 768, __launch_bounds__(512,3).
// Round-7 lesson: dur identical at 2x occupancy -> VALU-issue bound with ~40%
// bubbles. This round: (1) fences relaxed to groups (4 in A, 2 in D) for
// cross-n ILP + load prefetch, bounded hoisting; (2) softplus in log2 domain
// (d = log2(1+2^(s*log2e)); exp-arg = d*An since ln2*log2e = 1) - no libcall;
// (3) exclusive shift via DPP wave_shr:1 (VALU) instead of 32 ds_bpermute;
// (4) carry pre-stage: cb_s[w][n] computed once by 128 threads, then 16
// broadcast LDS reads/thread instead of ~112.

#if __has_builtin(__builtin_amdgcn_update_dpp)
#define HAVE_DPP 1
template<int CTRL, int RM>
__device__ __forceinline__ float updpp(float oldv, float src) {
    int r = __builtin_amdgcn_update_dpp(__builtin_bit_cast(int, oldv),
                                        __builtin_bit_cast(int, src),
                                        CTRL, RM, 0xF, false);
    return __builtin_bit_cast(float, r);
}
#else
#define HAVE_DPP 0
#endif

__global__ __launch_bounds__(512, 3) void k_scan(const float* __restrict__ xdbl,
                                                 const float* __restrict__ dtw,
                                                 const float* __restrict__ dtb,
                                                 const float* __restrict__ alogs,
                                                 const float* __restrict__ dsv_,
                                                 const float* __restrict__ x,
                                                 float* __restrict__ ys) {
    int bid = blockIdx.x;
    int k = bid & 7;                 // XCD swizzle: k == XCD id
    int d = bid >> 3;
    int kd = k * D_ + d;
    int t = threadIdx.x;
    int lane = t & 63, wv = t >> 6;  // wv in 0..7
    int l0t = t * 8;

    __shared__ float An_s[16];
    __shared__ float agg_a[8][16], agg_b[8][16];
    __shared__ float cb_s[8][16];
    if (t < 16)
        An_s[t] = -expf(alogs[kd * N_ + t]);   // exp-arg = d(l2) * An  (ln2*log2e=1)

#define DECL(n) float sA##n, sB##n;
    REPN(DECL)
#undef DECL
#define DECL(i) float d##i, u##i, y##i;
    REP8(DECL)
#undef DECL

    // ---- delta (fused): 8 elements; d holds log2(1+e^s) ----
    const float* xr = xdbl + k * CDBL * L_;
    const float2* wp2 = (const float2*)(dtw + kd * R_);
    const float2 w01 = wp2[0], w23 = wp2[1], w45 = wp2[2];
    const float bias = dtb[kd];
    const float dval = dsv_[kd];
#define SPL2(dst, s) { float p = (s) * LOG2E; \
    float l2 = LOG2F(1.f + EXP2(p)); \
    dst = ((s) > 20.f) ? p : l2; }
#define DLTQ(j, i0, i1, i2, i3) { \
    const float4 r0 = *(const float4*)(xr + 0 * L_ + l0t + j * 4); \
    const float4 r1 = *(const float4*)(xr + 1 * L_ + l0t + j * 4); \
    const float4 r2 = *(const float4*)(xr + 2 * L_ + l0t + j * 4); \
    const float4 r3 = *(const float4*)(xr + 3 * L_ + l0t + j * 4); \
    const float4 r4 = *(const float4*)(xr + 4 * L_ + l0t + j * 4); \
    const float4 r5 = *(const float4*)(xr + 5 * L_ + l0t + j * 4); \
    float s; \
    s = fmaf(w01.x, r0.x, bias); s = fmaf(w01.y, r1.x, s); s = fmaf(w23.x, r2.x, s); \
    s = fmaf(w23.y, r3.x, s); s = fmaf(w45.x, r4.x, s); s = fmaf(w45.y, r5.x, s); \
    SPL2(d##i0, s) \
    s = fmaf(w01.x, r0.y, bias); s = fmaf(w01.y, r1.y, s); s = fmaf(w23.x, r2.y, s); \
    s = fmaf(w23.y, r3.y, s); s = fmaf(w45.x, r4.y, s); s = fmaf(w45.y, r5.y, s); \
    SPL2(d##i1, s) \
    s = fmaf(w01.x, r0.z, bias); s = fmaf(w01.y, r1.z, s); s = fmaf(w23.x, r2.z, s); \
    s = fmaf(w23.y, r3.z, s); s = fmaf(w45.x, r4.z, s); s = fmaf(w45.y, r5.z, s); \
    SPL2(d##i2, s) \
    s = fmaf(w01.x, r0.w, bias); s = fmaf(w01.y, r1.w, s); s = fmaf(w23.x, r2.w, s); \
    s = fmaf(w23.y, r3.w, s); s = fmaf(w45.x, r4.w, s); s = fmaf(w45.y, r5.w, s); \
    SPL2(d##i3, s) }
    DLTQ(0, 0, 1, 2, 3)
    DLTQ(1, 4, 5, 6, 7)
#undef DLTQ
#undef SPL2

    // ---- u gather; y = Ds*u; u -> delta*u = u * ln2 * d(l2) ----
    const float* xd = x + d * L_;
#define UG(i) u##i = xd[src_index(k, l0t + i)]; y##i = dval * u##i; \
    u##i *= LN2F; u##i *= d##i;
    REP8(UG)
#undef UG

    __syncthreads();   // An_s ready

    const float* Bptr = xdbl + (k * CDBL + R_) * L_ + l0t;
    const float* Cptr = Bptr + N_ * L_;

    // ---- Phase A: per-n local (a,b) segment aggregates ----
#define PHA_E(i, Bc) { float e = EXP2(d##i * An); \
    rb = fmaf(e, rb, u##i * (Bc)); ra *= e; }
#define PHA(n) { \
    const float An = An_s[n]; \
    const float* Bn = Bptr + n * L_; \
    const float4 b0 = *(const float4*)(Bn), b1 = *(const float4*)(Bn + 4); \
    float ra = 1.f, rb = 0.f; \
    PHA_E(0, b0.x) PHA_E(1, b0.y) PHA_E(2, b0.z) PHA_E(3, b0.w) \
    PHA_E(4, b1.x) PHA_E(5, b1.y) PHA_E(6, b1.z) PHA_E(7, b1.w) \
    sA##n = ra; sB##n = rb; }
    PHA(0) PHA(1) PHA(2) PHA(3) FENCE
    PHA(4) PHA(5) PHA(6) PHA(7) FENCE
    PHA(8) PHA(9) PHA(10) PHA(11) FENCE
    PHA(12) PHA(13) PHA(14) PHA(15) FENCE
#undef PHA
#undef PHA_E

    // ---- Phase B: 64-lane inclusive scan of 16 scalar (a,b) pairs ----
#if HAVE_DPP
#define SSTN(n) { float pa = updpp<SC_CTRL, SC_RM>(1.f, sA##n); \
                  float pb = updpp<SC_CTRL, SC_RM>(0.f, sB##n); \
                  sB##n = fmaf(sA##n, pb, sB##n); sA##n *= pa; }
#define SC_CTRL 0x111
#define SC_RM 0xF
    REPN(SSTN)            // row_shr:1
#undef SC_CTRL
#undef SC_RM
#define SC_CTRL 0x112
#define SC_RM 0xF
    REPN(SSTN)            // row_shr:2
#undef SC_CTRL
#undef SC_RM
#define SC_CTRL 0x114
#define SC_RM 0xF
    REPN(SSTN)            // row_shr:4
#undef SC_CTRL
#undef SC_RM
#define SC_CTRL 0x118
#define SC_RM 0xF
    REPN(SSTN)            // row_shr:8
#undef SC_CTRL
#undef SC_RM
#define SC_CTRL 0x142
#define SC_RM 0xA
    REPN(SSTN)            // row_bcast:15 -> rows 1,3
#undef SC_CTRL
#undef SC_RM
#define SC_CTRL 0x143
#define SC_RM 0xC
    REPN(SSTN)            // row_bcast:31 -> rows 2,3
#undef SC_CTRL
#undef SC_RM
#undef SSTN

    // exclusive prefix via DPP wave_shr:1 (lane0 keeps identity); store aggs
#define PPREF(n) { \
    if (lane == 63) { agg_a[wv][n] = sA##n; agg_b[wv][n] = sB##n; } \
    sA##n = updpp<0x138, 0xF>(1.f, sA##n); \
    sB##n = updpp<0x138, 0xF>(0.f, sB##n); }
    REPN(PPREF)
#undef PPREF
#else
#define PBF(n) { float pa = __shfl_up(sA##n, off); float pb = __shfl_up(sB##n, off); \
    if (lane >= off) { sB##n = fmaf(sA##n, pb, sB##n); sA##n *= pa; } }
    for (int off = 1; off < 64; off <<= 1) { REPN(PBF) }
#undef PBF
#define PPREF(n) { float ia = sA##n, ib = sB##n; \
    float ea = __shfl_up(ia, 1); float eb = __shfl_up(ib, 1); \
    if (lane == 0) { ea = 1.f; eb = 0.f; } \
    if (lane == 63) { agg_a[wv][n] = ia; agg_b[wv][n] = ib; } \
    sA##n = ea; sB##n = eb; }
    REPN(PPREF)
#undef PPREF
#endif
    __syncthreads();

    // ---- Phase C: carry pre-stage (128 threads), then 1 broadcast read/n ----
    if (t < 128) {
        int w = t >> 4, n = t & 15;
        float cb = 0.f;
        for (int w2 = 0; w2 < w; ++w2)
            cb = fmaf(agg_a[w2][n], cb, agg_b[w2][n]);
        cb_s[w][n] = cb;
    }
    __syncthreads();
#define PC(n) { sA##n = fmaf(sA##n, cb_s[wv][n], sB##n); }
    REPN(PC)
#undef PC

    // ---- Phase D: plain recurrence from h_enter; y += C*h ----
#define PHD_E(i, Bc, Cc) { float e = EXP2(d##i * An); \
    h = fmaf(e, h, u##i * (Bc)); y##i = fmaf((Cc), h, y##i); }
#define PHD(n) { \
    const float An = An_s[n]; float h = sA##n; \
    const float* Bn = Bptr + n * L_; const float* Cn = Cptr + n * L_; \
    const float4 b0 = *(const float4*)(Bn), b1 = *(const float4*)(Bn + 4); \
    const float4 c0 = *(const float4*)(Cn), c1 = *(const float4*)(Cn + 4); \
    PHD_E(0, b0.x, c0.x) PHD_E(1, b0.y, c0.y) PHD_E(2, b0.z, c0.z) PHD_E(3, b0.w, c0.w) \
    PHD_E(4, b1.x, c1.x) PHD_E(5, b1.y, c1.y) PHD_E(6, b1.z, c1.z) PHD_E(7, b1.w, c1.w) }
    PHD(0) PHD(1) FENCE
    PHD(2) PHD(3) FENCE
    PHD(4) PHD(5) FENCE
    PHD(6) PHD(7) FENCE
    PHD(8) PHD(9) FENCE
    PHD(10) PHD(11) FENCE
    PHD(12) PHD(13) FENCE
    PHD(14) PHD(15) FENCE
#undef PHD
#undef PHD_E

    float* yp = ys + kd * L_ + l0t;
    {
        float4 o;
        o.x = y0; o.y = y1; o.z = y2; o.w = y3; *(float4*)(yp + 0) = o;
        o.x = y4; o.y = y5; o.z = y6; o.w = y7; *(float4*)(yp + 4) = o;
    }
}

// ---------------- K_C: cross_merge + LayerNorm fused ----------------
// grid 128 blocks x 32 positions; block 256
__global__ __launch_bounds__(256) void k_merge_ln(const float* __restrict__ ys,
                                                  const float* __restrict__ gamma,
                                                  const float* __restrict__ beta,
                                                  float* __restrict__ out) {
    __shared__ float sm[32][D_ + 1];
    __shared__ float mu_s[32], rs_s[32];
    int l0 = blockIdx.x * 32;
    for (int e = threadIdx.x; e < 32 * D_; e += 256) {
        int li = e & 31, d = e >> 5;
        int l = l0 + li;
        int h = l >> 6, w = l & 63;
        int i1 = (w << 6) + h;
        int i4 = (((w - h) & 63) << 6) + h;
        int i5 = (((w + h) & 63) << 6) + h;
        const float* bd = ys + d * L_;
        float v = bd[0 * DL_ + l] + bd[2 * DL_ + 4095 - l]
                + bd[1 * DL_ + i1] + bd[3 * DL_ + 4095 - i1]
                + bd[4 * DL_ + i4] + bd[6 * DL_ + 4095 - i4]
                + bd[5 * DL_ + i5] + bd[7 * DL_ + 4095 - i5];
        sm[li][d] = v;
    }
    __syncthreads();
    int li2 = threadIdx.x >> 3, sub = threadIdx.x & 7;
    float s = 0.f, sq = 0.f;
    for (int d = sub; d < D_; d += 8) {
        float v = sm[li2][d];
        s += v; sq = fmaf(v, v, sq);
    }
    s += __shfl_xor(s, 1); sq += __shfl_xor(sq, 1);
    s += __shfl_xor(s, 2); sq += __shfl_xor(sq, 2);
    s += __shfl_xor(s, 4); sq += __shfl_xor(sq, 4);
    if (sub == 0) {
        float mu = s * (1.f / 96.f);
        float var = sq * (1.f / 96.f) - mu * mu;
        mu_s[li2] = mu;
        rs_s[li2] = rsqrtf(var + 1e-5f);
    }
    __syncthreads();
    for (int e = threadIdx.x; e < 32 * D_; e += 256) {
        int li = e / D_, d = e - li * D_;
        float v = (sm[li][d] - mu_s[li]) * rs_s[li];
        out[(l0 + li) * D_ + d] = fmaf(v, gamma[d], beta[d]);
    }
}

extern "C" void kernel_launch(void* const* d_in, const int* in_sizes, int n_in,
                              void* d_out, int out_size, void* d_ws, size_t ws_size,
                              hipStream_t stream) {
    const float* x     = (const float*)d_in[0];
    const float* wproj = (const float*)d_in[1];
    const float* dtw   = (const float*)d_in[2];
    const float* dtb   = (const float*)d_in[3];
    const float* alogs = (const float*)d_in[4];
    const float* dsv   = (const float*)d_in[5];
    const float* gamma = (const float*)d_in[6];
    const float* beta  = (const float*)d_in[7];
    float* out = (float*)d_out;
    float* ws  = (float*)d_ws;

    float* xdbl = ws;                 // K*CDBL*L = 1,245,184 floats
    float* ysb  = ws + 1245184;       // K*D*L    = 3,145,728 floats

    hipLaunchKernelGGL(k_xdbl, dim3(512), dim3(256), 0, stream, x, wproj, xdbl);
    hipLaunchKernelGGL(k_scan, dim3(768), dim3(512), 0, stream,
                       xdbl, dtw, dtb, alogs, dsv, x, ysb);
    hipLaunchKernelGGL(k_merge_ln, dim3(128), dim3(256), 0, stream,
                       ysb, gamma, beta, out);
}